// Round 1
// 693.896 us; speedup vs baseline: 1.0435x; 1.0435x over previous
//
#include <hip/hip_runtime.h>

// ---------------------------------------------------------------------------
// TiedMultiheadAttention  (B=1, N=64, L=512, D=768, H=12, DK=64)
//
// R3: all GEMMs on the bf16 global_load_lds(16B) path. Q/K/V are converted
//     fp32->bf16 in a streaming pass (scratch = d_out, dead until s5);
//     Wq/Wk/Wv/Wo converted in one fused launch (scratch = att region,
//     dead until the s2 memset). F32S in-GEMM staging retired.
// ---------------------------------------------------------------------------

typedef __bf16 bf16x8 __attribute__((ext_vector_type(8)));
typedef float f32x4 __attribute__((ext_vector_type(4)));

__device__ __forceinline__ unsigned short f2bf(float f) {
  unsigned u = __float_as_uint(f);
  u += 0x7fffu + ((u >> 16) & 1u);  // RNE
  return (unsigned short)(u >> 16);
}

__device__ __forceinline__ void gll16(const unsigned short* g, unsigned short* l) {
  __builtin_amdgcn_global_load_lds(
      (const __attribute__((address_space(1))) unsigned int*)g,
      (__attribute__((address_space(3))) unsigned int*)l, 16, 0, 0);
}

template <bool C, typename T1, typename T2> struct Cond { using type = T1; };
template <typename T1, typename T2> struct Cond<false, T1, T2> { using type = T2; };

enum { MODE_QCAT = 0, MODE_VT = 1, MODE_ATT = 2, MODE_OUTWS = 3, MODE_OUT_BIAS = 4 };

constexpr int BM = 128, BN = 128, BK = 32;

// C = A @ B^T. A:[M,K] lda, B:[N,K] ldb. Batch via blockIdx.z (opt split-K).
// F32S: A/B are fp32, converted to bf16 in VGPRs during staging (padded LDS).
// else: A/B bf16, staged via global_load_lds (unpadded m97 layout).
// SWZ : XCD-aware block swizzle, requires ntiles_m % 8 == 0, 1-D grid.
template <int MODE, bool F32S, bool SWZ, int KS>
__global__ __launch_bounds__(256, 2) void gemm_bt(
    const void* __restrict__ Av, const void* __restrict__ Bv,
    const float* __restrict__ bias, void* __restrict__ Cv,
    int K, int lda, int ldb, long long a_bs, long long b_bs,
    float alpha, int ntn) {
  using T = typename Cond<F32S, float, unsigned short>::type;
  constexpr int LP = F32S ? 40 : 32;  // row stride in bf16 elems

  __shared__ unsigned short As[BM * LP];
  __shared__ unsigned short Bs[BN * LP];

  const int tid = threadIdx.x;
  const int wave = tid >> 6;
  const int lane = tid & 63;
  const int wm = wave >> 1, wn = wave & 1;

  int tm, tn;
  if constexpr (SWZ) {
    const int bid = blockIdx.x;
    const int xcd = bid & 7;
    const int k = bid >> 3;
    tn = k % ntn;
    tm = (k / ntn) * 8 + xcd;
  } else {
    tn = blockIdx.x;
    tm = blockIdx.y;
  }
  int batch = blockIdx.z, ks = 0;
  if constexpr (KS > 1) { ks = batch % KS; batch /= KS; }

  const long long m0 = (long long)tm * BM;
  const long long n0 = (long long)tn * BN;

  const T* Ab = (const T*)Av + (long long)batch * a_bs + (long long)ks * K;
  const T* Bb = (const T*)Bv + (long long)batch * b_bs + (long long)ks * K;

  f32x4 acc[4][4] = {};

  const int l15 = lane & 15;
  const int kq = (lane >> 4) * 8;

  for (int k0 = 0; k0 < K; k0 += BK) {
    if constexpr (F32S) {
      const int row = tid >> 3;          // 0..31
      const int c4 = (tid & 7) * 4;      // 0,4,..,28
#pragma unroll
      for (int rr = 0; rr < 4; ++rr) {
        const int r = row + rr * 32;
        const float4 av = *(const float4*)((const float*)Ab + (m0 + r) * (long long)lda + k0 + c4);
        const float4 bv = *(const float4*)((const float*)Bb + (n0 + r) * (long long)ldb + k0 + c4);
        ushort4 ap{f2bf(av.x), f2bf(av.y), f2bf(av.z), f2bf(av.w)};
        ushort4 bp{f2bf(bv.x), f2bf(bv.y), f2bf(bv.z), f2bf(bv.w)};
        *(ushort4*)&As[r * LP + c4] = ap;
        *(ushort4*)&Bs[r * LP + c4] = bp;
      }
    } else {
      const int r_in = lane >> 2;        // 0..15
      const int c8 = (lane & 3) * 8;     // 0,8,16,24
#pragma unroll
      for (int t = 0; t < 2; ++t) {
        const int rb = t * 64 + wave * 16;  // wave-uniform row base
        gll16((const unsigned short*)Ab + (m0 + rb + r_in) * (long long)lda + k0 + c8,
              &As[rb * LP]);
        gll16((const unsigned short*)Bb + (n0 + rb + r_in) * (long long)ldb + k0 + c8,
              &Bs[rb * LP]);
      }
    }
    __syncthreads();

    bf16x8 af[4], bfr[4];
#pragma unroll
    for (int t = 0; t < 4; ++t)
      af[t] = *(const bf16x8*)&As[(wm * 64 + t * 16 + l15) * LP + kq];
#pragma unroll
    for (int u = 0; u < 4; ++u)
      bfr[u] = *(const bf16x8*)&Bs[(wn * 64 + u * 16 + l15) * LP + kq];
#pragma unroll
    for (int t = 0; t < 4; ++t)
#pragma unroll
      for (int u = 0; u < 4; ++u)
        acc[t][u] = __builtin_amdgcn_mfma_f32_16x16x32_bf16(af[t], bfr[u], acc[t][u], 0, 0, 0);
    __syncthreads();
  }

  // Epilogue: D[m][n] with m_rel=(lane>>4)*4+r, n_rel=lane&15 per 16x16 tile
#pragma unroll
  for (int t = 0; t < 4; ++t) {
#pragma unroll
    for (int u = 0; u < 4; ++u) {
      const long long col = n0 + wn * 64 + u * 16 + l15;
#pragma unroll
      for (int r = 0; r < 4; ++r) {
        const long long row = m0 + wm * 64 + t * 16 + (lane >> 4) * 4 + r;
        float v = acc[t][u][r];
        if constexpr (MODE == MODE_QCAT) {
          v = (v + bias[col]) * alpha;
          const long long h = col >> 6, kk = col & 63, n = row >> 9, i = row & 511;
          ((unsigned short*)Cv)[((h * 512 + i) << 12) + (n << 6) + kk] = f2bf(v);
        } else if constexpr (MODE == MODE_VT) {
          v = v + bias[col];
          const long long h = col >> 6, kk = col & 63, n = row >> 9, j = row & 511;
          ((unsigned short*)Cv)[(((h << 12) + (n << 6) + kk) << 9) + j] = f2bf(v);
        } else if constexpr (MODE == MODE_ATT) {
          float* p = &((float*)Cv)[((long long)batch << 18) + (row << 9) + col];
          if constexpr (KS > 1) atomicAdd(p, v); else *p = v;
        } else if constexpr (MODE == MODE_OUTWS) {
          const long long n = col >> 6, kk = col & 63;
          ((unsigned short*)Cv)[(n * 512 + row) * 768 + (long long)batch * 64 + kk] = f2bf(v);
        } else {  // MODE_OUT_BIAS
          ((float*)Cv)[row * 768 + col] = v + bias[col];
        }
      }
    }
  }
}

// softmax over last dim: att fp32 [12][512][512] -> bf16
__global__ __launch_bounds__(256) void softmax_rows(const float* __restrict__ att,
                                                    unsigned short* __restrict__ outb) {
  const long long rowbase = (long long)blockIdx.x << 9;
  const int tid = threadIdx.x;
  float a = att[rowbase + tid];
  float b = att[rowbase + tid + 256];

  float m = fmaxf(a, b);
#pragma unroll
  for (int off = 32; off; off >>= 1) m = fmaxf(m, __shfl_down(m, off));
  __shared__ float redm[4];
  if ((tid & 63) == 0) redm[tid >> 6] = m;
  __syncthreads();
  m = fmaxf(fmaxf(redm[0], redm[1]), fmaxf(redm[2], redm[3]));

  const float e0 = __expf(a - m), e1 = __expf(b - m);
  float s = e0 + e1;
#pragma unroll
  for (int off = 32; off; off >>= 1) s += __shfl_down(s, off);
  __shared__ float reds[4];
  if ((tid & 63) == 0) reds[tid >> 6] = s;
  __syncthreads();
  s = reds[0] + reds[1] + reds[2] + reds[3];

  const float inv = 1.0f / s;
  outb[rowbase + tid] = f2bf(e0 * inv);
  outb[rowbase + tid + 256] = f2bf(e1 * inv);
}

// fp32 -> bf16, 8 elems/thread (n must be multiple of 2048)
__global__ __launch_bounds__(256) void cvt_bf16(const float* __restrict__ in,
                                                unsigned short* __restrict__ out) {
  const long long i = ((long long)blockIdx.x * 256 + threadIdx.x) * 8;
  const float4 a = *(const float4*)(in + i);
  const float4 b = *(const float4*)(in + i + 4);
  uint4 p;
  p.x = (unsigned)f2bf(a.x) | ((unsigned)f2bf(a.y) << 16);
  p.y = (unsigned)f2bf(a.z) | ((unsigned)f2bf(a.w) << 16);
  p.z = (unsigned)f2bf(b.x) | ((unsigned)f2bf(b.y) << 16);
  p.w = (unsigned)f2bf(b.z) | ((unsigned)f2bf(b.w) << 16);
  *(uint4*)(out + i) = p;
}

// fp32 -> bf16 for the four 768x768 weights in one launch (blockIdx.y picks tensor)
__global__ __launch_bounds__(256) void cvt_w4(
    const float* __restrict__ s0, const float* __restrict__ s1,
    const float* __restrict__ s2, const float* __restrict__ s3,
    unsigned short* __restrict__ d0, unsigned short* __restrict__ d1,
    unsigned short* __restrict__ d2, unsigned short* __restrict__ d3) {
  const float* s;
  unsigned short* d;
  switch (blockIdx.y) {
    case 0: s = s0; d = d0; break;
    case 1: s = s1; d = d1; break;
    case 2: s = s2; d = d2; break;
    default: s = s3; d = d3; break;
  }
  const long long i = ((long long)blockIdx.x * 256 + threadIdx.x) * 8;
  const float4 a = *(const float4*)(s + i);
  const float4 b = *(const float4*)(s + i + 4);
  uint4 p;
  p.x = (unsigned)f2bf(a.x) | ((unsigned)f2bf(a.y) << 16);
  p.y = (unsigned)f2bf(a.z) | ((unsigned)f2bf(a.w) << 16);
  p.z = (unsigned)f2bf(b.x) | ((unsigned)f2bf(b.y) << 16);
  p.w = (unsigned)f2bf(b.z) | ((unsigned)f2bf(b.w) << 16);
  *(uint4*)(d + i) = p;
}

extern "C" void kernel_launch(void* const* d_in, const int* in_sizes, int n_in,
                              void* d_out, int out_size, void* d_ws, size_t ws_size,
                              hipStream_t stream) {
  const float* query = (const float*)d_in[0];
  const float* key   = (const float*)d_in[1];
  const float* value = (const float*)d_in[2];
  const float* Wq = (const float*)d_in[3];
  const float* bq = (const float*)d_in[4];
  const float* Wk = (const float*)d_in[5];
  const float* bk = (const float*)d_in[6];
  const float* Wv = (const float*)d_in[7];
  const float* bv = (const float*)d_in[8];
  const float* Wo = (const float*)d_in[9];
  const float* bo = (const float*)d_in[10];
  float* out = (float*)d_out;

  char* ws = (char*)d_ws;
  unsigned short* q_ws  = (unsigned short*)(ws);               // 50,331,648 B
  unsigned short* k_ws  = (unsigned short*)(ws + 50331648);    // 50,331,648 B
  unsigned short* vt_ws = (unsigned short*)(ws + 100663296);   // 50,331,648 B
  float*          att   = (float*)(ws + 150994944);            // 12,582,912 B
  unsigned short* wo_b  = (unsigned short*)(ws + 163577856);   //  1,179,648 B
  // bf16 weight copies live in the att region (dead until the s2 memset)
  unsigned short* wq_b  = (unsigned short*)(ws + 150994944);
  unsigned short* wk_b  = (unsigned short*)(ws + 150994944 + 1179648);
  unsigned short* wv_b  = (unsigned short*)(ws + 150994944 + 2359296);
  unsigned short* att_b = k_ws;   // k_ws dead after s2
  unsigned short* out_ws = q_ws;  // q_ws dead after s2
  // bf16 input scratch: d_out is dead until s5 (fully overwritten there)
  unsigned short* xb = (unsigned short*)d_out;  // 50,331,648 B <= out_size

  const dim3 blk(256);

  // s0: all four weights fp32 -> bf16 (589824 elems = 288 * 2048 each)
  cvt_w4<<<dim3(288, 4), blk, 0, stream>>>(Wo, Wq, Wk, Wv, wo_b, wq_b, wk_b, wv_b);

  // s1: projections — convert input to bf16 (stream-serialized into xb),
  //     then m97-style bf16 GEMM with global_load_lds staging.
  //     25,165,824 elems = 12288 * 2048. XCD swizzle (ntm=256, ntn=6).
  cvt_bf16<<<12288, blk, 0, stream>>>(query, xb);
  gemm_bt<MODE_QCAT, false, true, 1><<<dim3(1536, 1, 1), blk, 0, stream>>>(
      xb, wq_b, bq, q_ws, 768, 768, 768, 0, 0, 0.015625f, 6);
  cvt_bf16<<<12288, blk, 0, stream>>>(key, xb);
  gemm_bt<MODE_QCAT, false, true, 1><<<dim3(1536, 1, 1), blk, 0, stream>>>(
      xb, wk_b, bk, k_ws, 768, 768, 768, 0, 0, 1.0f, 6);
  cvt_bf16<<<12288, blk, 0, stream>>>(value, xb);
  gemm_bt<MODE_VT, false, true, 1><<<dim3(1536, 1, 1), blk, 0, stream>>>(
      xb, wv_b, bv, vt_ws, 768, 768, 768, 0, 0, 1.0f, 6);

  // s2: tied scores, per-head [512 x 4096] @ [512 x 4096]^T, split-K x4
  hipMemsetAsync(att, 0, 12582912, stream);
  gemm_bt<MODE_ATT, false, false, 4><<<dim3(4, 4, 48), blk, 0, stream>>>(
      q_ws, k_ws, nullptr, att, 1024, 4096, 4096, 2097152LL, 2097152LL, 1.0f, 4);

  // s3: softmax
  softmax_rows<<<6144, blk, 0, stream>>>(att, att_b);

  // s4: per-head att @ Vt^T -> out_ws [(n*512+i)][h*64+k]
  gemm_bt<MODE_OUTWS, false, false, 1><<<dim3(32, 4, 12), blk, 0, stream>>>(
      att_b, vt_ws, nullptr, out_ws, 512, 512, 512, 262144LL, 2097152LL, 1.0f, 32);

  // s5: output projection -> fp32 d_out, XCD swizzle
  gemm_bt<MODE_OUT_BIAS, false, true, 1><<<dim3(1536, 1, 1), blk, 0, stream>>>(
      out_ws, wo_b, bo, out, 768, 768, 768, 0, 0, 1.0f, 6);
}

// Round 2
// 668.225 us; speedup vs baseline: 1.0836x; 1.0384x over previous
//
#include <hip/hip_runtime.h>

// ---------------------------------------------------------------------------
// TiedMultiheadAttention  (B=1, N=64, L=512, D=768, H=12, DK=64)
//
// R4: XCD-locality block maps for s2 (tied scores) and s4 (att@V): blocks
//     sharing A/B panels are congruent mod 8 -> same XCD L2, co-resident.
//     Q+K cvt fused into one launch; Q+K projection GEMMs batched (z=2).
// ---------------------------------------------------------------------------

typedef __bf16 bf16x8 __attribute__((ext_vector_type(8)));
typedef float f32x4 __attribute__((ext_vector_type(4)));

__device__ __forceinline__ unsigned short f2bf(float f) {
  unsigned u = __float_as_uint(f);
  u += 0x7fffu + ((u >> 16) & 1u);  // RNE
  return (unsigned short)(u >> 16);
}

__device__ __forceinline__ void gll16(const unsigned short* g, unsigned short* l) {
  __builtin_amdgcn_global_load_lds(
      (const __attribute__((address_space(1))) unsigned int*)g,
      (__attribute__((address_space(3))) unsigned int*)l, 16, 0, 0);
}

enum { MODE_QCAT = 0, MODE_VT = 1, MODE_ATT = 2, MODE_OUTWS = 3, MODE_OUT_BIAS = 4 };

constexpr int BM = 128, BN = 128, BK = 32;

// C = A @ B^T. A:[M,K] lda, B:[N,K] ldb. bf16 inputs, global_load_lds staging.
// SWZ block maps:
//   MODE_ATT  : 1-D grid 768 = 48 z x 16 tiles; all 16 tiles of one z on one XCD.
//   MODE_OUTWS: 1-D grid 1536 = 24 (head,half) groups x 64 tiles; group on one XCD.
//   other     : generic XCD swizzle (ntiles_m % 8 == 0), z = batch.
// Batched QCAT: bias2/alpha2/c_bs select per-batch bias, scale, C base.
template <int MODE, bool SWZ, int KS>
__global__ __launch_bounds__(256, 2) void gemm_bt(
    const void* __restrict__ Av, const void* __restrict__ Bv,
    const float* __restrict__ bias, void* __restrict__ Cv,
    int K, int lda, int ldb, long long a_bs, long long b_bs,
    float alpha, int ntn,
    const float* __restrict__ bias2, float alpha2, long long c_bs) {
  constexpr int LP = 32;  // row stride in bf16 elems

  __shared__ unsigned short As[BM * LP];
  __shared__ unsigned short Bs[BN * LP];

  const int tid = threadIdx.x;
  const int wave = tid >> 6;
  const int lane = tid & 63;
  const int wm = wave >> 1, wn = wave & 1;

  int tm, tn, batch = 0, ks = 0;
  if constexpr (SWZ && MODE == MODE_ATT) {
    const int bid = blockIdx.x;
    const int xcd = bid & 7, j = bid >> 3;
    const int z = (j >> 4) * 8 + xcd;   // 0..47, z%8 == xcd
    const int tile = j & 15;
    tn = tile & 3;
    tm = tile >> 2;
    ks = z % KS;
    batch = z / KS;
  } else if constexpr (SWZ && MODE == MODE_OUTWS) {
    const int bid = blockIdx.x;
    const int xcd = bid & 7, j = bid >> 3;
    const int g = (j >> 6) * 8 + xcd;   // 0..23, g%8 == xcd
    const int idx = j & 63;
    batch = g >> 1;                     // head
    tm = idx >> 4;
    tn = (g & 1) * 16 + (idx & 15);
  } else {
    if constexpr (SWZ) {
      const int bid = blockIdx.x;
      const int xcd = bid & 7;
      const int k = bid >> 3;
      tn = k % ntn;
      tm = (k / ntn) * 8 + xcd;
    } else {
      tn = blockIdx.x;
      tm = blockIdx.y;
    }
    batch = blockIdx.z;
    if constexpr (KS > 1) { ks = batch % KS; batch /= KS; }
  }

  const long long m0 = (long long)tm * BM;
  const long long n0 = (long long)tn * BN;

  const unsigned short* Ab = (const unsigned short*)Av + (long long)batch * a_bs + (long long)ks * K;
  const unsigned short* Bb = (const unsigned short*)Bv + (long long)batch * b_bs + (long long)ks * K;

  f32x4 acc[4][4] = {};

  const int l15 = lane & 15;
  const int kq = (lane >> 4) * 8;
  const int r_in = lane >> 2;        // 0..15
  const int c8 = (lane & 3) * 8;     // 0,8,16,24

  for (int k0 = 0; k0 < K; k0 += BK) {
#pragma unroll
    for (int t = 0; t < 2; ++t) {
      const int rb = t * 64 + wave * 16;  // wave-uniform row base
      gll16((const unsigned short*)Ab + (m0 + rb + r_in) * (long long)lda + k0 + c8,
            &As[rb * LP]);
      gll16((const unsigned short*)Bb + (n0 + rb + r_in) * (long long)ldb + k0 + c8,
            &Bs[rb * LP]);
    }
    __syncthreads();

    bf16x8 af[4], bfr[4];
#pragma unroll
    for (int t = 0; t < 4; ++t)
      af[t] = *(const bf16x8*)&As[(wm * 64 + t * 16 + l15) * LP + kq];
#pragma unroll
    for (int u = 0; u < 4; ++u)
      bfr[u] = *(const bf16x8*)&Bs[(wn * 64 + u * 16 + l15) * LP + kq];
#pragma unroll
    for (int t = 0; t < 4; ++t)
#pragma unroll
      for (int u = 0; u < 4; ++u)
        acc[t][u] = __builtin_amdgcn_mfma_f32_16x16x32_bf16(af[t], bfr[u], acc[t][u], 0, 0, 0);
    __syncthreads();
  }

  // Epilogue: D[m][n] with m_rel=(lane>>4)*4+r, n_rel=lane&15 per 16x16 tile
#pragma unroll
  for (int t = 0; t < 4; ++t) {
#pragma unroll
    for (int u = 0; u < 4; ++u) {
      const long long col = n0 + wn * 64 + u * 16 + l15;
#pragma unroll
      for (int r = 0; r < 4; ++r) {
        const long long row = m0 + wm * 64 + t * 16 + (lane >> 4) * 4 + r;
        float v = acc[t][u][r];
        if constexpr (MODE == MODE_QCAT) {
          const float* bb = batch ? bias2 : bias;
          const float aa = batch ? alpha2 : alpha;
          v = (v + bb[col]) * aa;
          const long long h = col >> 6, kk = col & 63, n = row >> 9, i = row & 511;
          ((unsigned short*)Cv + batch * c_bs)[((h * 512 + i) << 12) + (n << 6) + kk] = f2bf(v);
        } else if constexpr (MODE == MODE_VT) {
          v = v + bias[col];
          const long long h = col >> 6, kk = col & 63, n = row >> 9, j = row & 511;
          ((unsigned short*)Cv)[(((h << 12) + (n << 6) + kk) << 9) + j] = f2bf(v);
        } else if constexpr (MODE == MODE_ATT) {
          float* p = &((float*)Cv)[((long long)batch << 18) + (row << 9) + col];
          if constexpr (KS > 1) atomicAdd(p, v); else *p = v;
        } else if constexpr (MODE == MODE_OUTWS) {
          const long long n = col >> 6, kk = col & 63;
          ((unsigned short*)Cv)[(n * 512 + row) * 768 + (long long)batch * 64 + kk] = f2bf(v);
        } else {  // MODE_OUT_BIAS
          ((float*)Cv)[row * 768 + col] = v + bias[col];
        }
      }
    }
  }
}

// softmax over last dim: att fp32 [12][512][512] -> bf16
__global__ __launch_bounds__(256) void softmax_rows(const float* __restrict__ att,
                                                    unsigned short* __restrict__ outb) {
  const long long rowbase = (long long)blockIdx.x << 9;
  const int tid = threadIdx.x;
  float a = att[rowbase + tid];
  float b = att[rowbase + tid + 256];

  float m = fmaxf(a, b);
#pragma unroll
  for (int off = 32; off; off >>= 1) m = fmaxf(m, __shfl_down(m, off));
  __shared__ float redm[4];
  if ((tid & 63) == 0) redm[tid >> 6] = m;
  __syncthreads();
  m = fmaxf(fmaxf(redm[0], redm[1]), fmaxf(redm[2], redm[3]));

  const float e0 = __expf(a - m), e1 = __expf(b - m);
  float s = e0 + e1;
#pragma unroll
  for (int off = 32; off; off >>= 1) s += __shfl_down(s, off);
  __shared__ float reds[4];
  if ((tid & 63) == 0) reds[tid >> 6] = s;
  __syncthreads();
  s = reds[0] + reds[1] + reds[2] + reds[3];

  const float inv = 1.0f / s;
  outb[rowbase + tid] = f2bf(e0 * inv);
  outb[rowbase + tid + 256] = f2bf(e1 * inv);
}

// fp32 -> bf16, 8 elems/thread (n must be multiple of 2048)
__global__ __launch_bounds__(256) void cvt_bf16(const float* __restrict__ in,
                                                unsigned short* __restrict__ out) {
  const long long i = ((long long)blockIdx.x * 256 + threadIdx.x) * 8;
  const float4 a = *(const float4*)(in + i);
  const float4 b = *(const float4*)(in + i + 4);
  uint4 p;
  p.x = (unsigned)f2bf(a.x) | ((unsigned)f2bf(a.y) << 16);
  p.y = (unsigned)f2bf(a.z) | ((unsigned)f2bf(a.w) << 16);
  p.z = (unsigned)f2bf(b.x) | ((unsigned)f2bf(b.y) << 16);
  p.w = (unsigned)f2bf(b.z) | ((unsigned)f2bf(b.w) << 16);
  *(uint4*)(out + i) = p;
}

// fp32 -> bf16 for two big tensors in one launch (blockIdx.y picks tensor)
__global__ __launch_bounds__(256) void cvt_qk(
    const float* __restrict__ s0, const float* __restrict__ s1,
    unsigned short* __restrict__ d0, unsigned short* __restrict__ d1) {
  const float* s = blockIdx.y ? s1 : s0;
  unsigned short* d = blockIdx.y ? d1 : d0;
  const long long i = ((long long)blockIdx.x * 256 + threadIdx.x) * 8;
  const float4 a = *(const float4*)(s + i);
  const float4 b = *(const float4*)(s + i + 4);
  uint4 p;
  p.x = (unsigned)f2bf(a.x) | ((unsigned)f2bf(a.y) << 16);
  p.y = (unsigned)f2bf(a.z) | ((unsigned)f2bf(a.w) << 16);
  p.z = (unsigned)f2bf(b.x) | ((unsigned)f2bf(b.y) << 16);
  p.w = (unsigned)f2bf(b.z) | ((unsigned)f2bf(b.w) << 16);
  *(uint4*)(d + i) = p;
}

// fp32 -> bf16 for the four 768x768 weights in one launch
__global__ __launch_bounds__(256) void cvt_w4(
    const float* __restrict__ s0, const float* __restrict__ s1,
    const float* __restrict__ s2, const float* __restrict__ s3,
    unsigned short* __restrict__ d0, unsigned short* __restrict__ d1,
    unsigned short* __restrict__ d2, unsigned short* __restrict__ d3) {
  const float* s;
  unsigned short* d;
  switch (blockIdx.y) {
    case 0: s = s0; d = d0; break;
    case 1: s = s1; d = d1; break;
    case 2: s = s2; d = d2; break;
    default: s = s3; d = d3; break;
  }
  const long long i = ((long long)blockIdx.x * 256 + threadIdx.x) * 8;
  const float4 a = *(const float4*)(s + i);
  const float4 b = *(const float4*)(s + i + 4);
  uint4 p;
  p.x = (unsigned)f2bf(a.x) | ((unsigned)f2bf(a.y) << 16);
  p.y = (unsigned)f2bf(a.z) | ((unsigned)f2bf(a.w) << 16);
  p.z = (unsigned)f2bf(b.x) | ((unsigned)f2bf(b.y) << 16);
  p.w = (unsigned)f2bf(b.z) | ((unsigned)f2bf(b.w) << 16);
  *(uint4*)(d + i) = p;
}

extern "C" void kernel_launch(void* const* d_in, const int* in_sizes, int n_in,
                              void* d_out, int out_size, void* d_ws, size_t ws_size,
                              hipStream_t stream) {
  const float* query = (const float*)d_in[0];
  const float* key   = (const float*)d_in[1];
  const float* value = (const float*)d_in[2];
  const float* Wq = (const float*)d_in[3];
  const float* bq = (const float*)d_in[4];
  const float* Wk = (const float*)d_in[5];
  const float* bk = (const float*)d_in[6];
  const float* Wv = (const float*)d_in[7];
  const float* bv = (const float*)d_in[8];
  const float* Wo = (const float*)d_in[9];
  const float* bo = (const float*)d_in[10];
  float* out = (float*)d_out;

  char* ws = (char*)d_ws;
  unsigned short* q_ws  = (unsigned short*)(ws);               // 50,331,648 B
  unsigned short* k_ws  = (unsigned short*)(ws + 50331648);    // 50,331,648 B
  unsigned short* vt_ws = (unsigned short*)(ws + 100663296);   // 50,331,648 B
  float*          att   = (float*)(ws + 150994944);            // 12,582,912 B
  unsigned short* wo_b  = (unsigned short*)(ws + 163577856);   //  1,179,648 B
  // bf16 weight copies live in the att region (dead until the s2 memset)
  unsigned short* wq_b  = (unsigned short*)(ws + 150994944);
  unsigned short* wk_b  = (unsigned short*)(ws + 150994944 + 1179648);
  unsigned short* wv_b  = (unsigned short*)(ws + 150994944 + 2359296);
  unsigned short* att_b = k_ws;   // k_ws dead after s2
  unsigned short* out_ws = q_ws;  // q_ws dead after s2
  // bf16 input scratch: d_out is dead until s5 (fully overwritten there)
  unsigned short* xb0 = (unsigned short*)d_out;                 // 50,331,648 B
  unsigned short* xb1 = (unsigned short*)d_out + 25165824;      // 50,331,648 B

  const dim3 blk(256);

  // s0: all four weights fp32 -> bf16 (589824 elems = 288 * 2048 each)
  cvt_w4<<<dim3(288, 4), blk, 0, stream>>>(Wo, Wq, Wk, Wv, wo_b, wq_b, wk_b, wv_b);

  // s1a: query+key fp32 -> bf16 in one launch (25,165,824 elems = 12288*2048 each)
  cvt_qk<<<dim3(12288, 2), blk, 0, stream>>>(query, key, xb0, xb1);

  // s1b: Q and K projections batched (z=2): A,B,C batch-strided, per-batch bias/alpha
  gemm_bt<MODE_QCAT, true, 1><<<dim3(1536, 1, 2), blk, 0, stream>>>(
      xb0, wq_b, bq, q_ws, 768, 768, 768, 25165824LL, 589824LL, 0.015625f, 6,
      bk, 1.0f, 25165824LL);

  // s1c: value cvt + V projection
  cvt_bf16<<<12288, blk, 0, stream>>>(value, xb0);
  gemm_bt<MODE_VT, true, 1><<<dim3(1536, 1, 1), blk, 0, stream>>>(
      xb0, wv_b, bv, vt_ws, 768, 768, 768, 0, 0, 1.0f, 6, nullptr, 0.0f, 0);

  // s2: tied scores, per-head [512 x 4096] @ [512 x 4096]^T, split-K x4.
  //     Locality map: 16 tiles of one z=(head,ks) share 2 MB -> one XCD L2.
  hipMemsetAsync(att, 0, 12582912, stream);
  gemm_bt<MODE_ATT, true, 4><<<dim3(768, 1, 1), blk, 0, stream>>>(
      q_ws, k_ws, nullptr, att, 1024, 4096, 4096, 2097152LL, 2097152LL, 1.0f, 0,
      nullptr, 0.0f, 0);

  // s3: softmax
  softmax_rows<<<6144, blk, 0, stream>>>(att, att_b);

  // s4: per-head att @ Vt^T -> out_ws [(n*512+i)][h*64+k].
  //     Locality map: 64 tiles of one (head, N-half) share 2.5 MB -> one XCD L2.
  gemm_bt<MODE_OUTWS, true, 1><<<dim3(1536, 1, 1), blk, 0, stream>>>(
      att_b, vt_ws, nullptr, out_ws, 512, 512, 512, 262144LL, 2097152LL, 1.0f, 0,
      nullptr, 0.0f, 0);

  // s5: output projection -> fp32 d_out, generic XCD swizzle
  gemm_bt<MODE_OUT_BIAS, true, 1><<<dim3(1536, 1, 1), blk, 0, stream>>>(
      out_ws, wo_b, bo, out, 768, 768, 768, 0, 0, 1.0f, 6, nullptr, 0.0f, 0);
}

// Round 3
// 643.314 us; speedup vs baseline: 1.1256x; 1.0387x over previous
//
#include <hip/hip_runtime.h>

// ---------------------------------------------------------------------------
// TiedMultiheadAttention  (B=1, N=64, L=512, D=768, H=12, DK=64)
//
// R5: double-buffered LDS + counted-vmcnt pipeline (T4 minimal form) in all
//     GEMMs: STAGE(next); s_waitcnt vmcnt(4); raw s_barrier; compute(cur).
//     Next-tile global_load_lds stay in flight across barriers — removes the
//     ~900cy per-K-step cold-miss drain that made s1b latency-bound.
//     Bias preloaded to registers pre-loop (keeps vmcnt counting exact).
// ---------------------------------------------------------------------------

typedef __bf16 bf16x8 __attribute__((ext_vector_type(8)));
typedef float f32x4 __attribute__((ext_vector_type(4)));

__device__ __forceinline__ unsigned short f2bf(float f) {
  unsigned u = __float_as_uint(f);
  u += 0x7fffu + ((u >> 16) & 1u);  // RNE
  return (unsigned short)(u >> 16);
}

__device__ __forceinline__ void gll16(const unsigned short* g, unsigned short* l) {
  __builtin_amdgcn_global_load_lds(
      (const __attribute__((address_space(1))) unsigned int*)g,
      (__attribute__((address_space(3))) unsigned int*)l, 16, 0, 0);
}

#define VMCNT_4 asm volatile("s_waitcnt vmcnt(4)" ::: "memory")
#define VMCNT_0 asm volatile("s_waitcnt vmcnt(0)" ::: "memory")
#define BAR __builtin_amdgcn_s_barrier()

enum { MODE_QCAT = 0, MODE_VT = 1, MODE_ATT = 2, MODE_OUTWS = 3, MODE_OUT_BIAS = 4 };

constexpr int BM = 128, BN = 128, BK = 32;

// C = A @ B^T. A:[M,K] lda, B:[N,K] ldb. bf16 inputs, global_load_lds staging,
// double-buffered with counted vmcnt. Requires K % 64 == 0 (even # K-steps).
// SWZ block maps:
//   MODE_ATT  : 1-D grid 768 = 48 z x 16 tiles; all 16 tiles of one z on one XCD.
//   MODE_OUTWS: 1-D grid 1536 = 24 (head,half) groups x 64 tiles; group on one XCD.
//   other     : generic XCD swizzle (ntiles_m % 8 == 0), z = batch.
// Batched QCAT: bias2/alpha2/c_bs select per-batch bias, scale, C base.
template <int MODE, bool SWZ, int KS>
__global__ __launch_bounds__(256, 2) void gemm_bt(
    const void* __restrict__ Av, const void* __restrict__ Bv,
    const float* __restrict__ bias, void* __restrict__ Cv,
    int K, int lda, int ldb, long long a_bs, long long b_bs,
    float alpha, int ntn,
    const float* __restrict__ bias2, float alpha2, long long c_bs) {
  constexpr int LP = 32;  // row stride in bf16 elems

  __shared__ unsigned short As0[BM * LP];
  __shared__ unsigned short Bs0[BN * LP];
  __shared__ unsigned short As1[BM * LP];
  __shared__ unsigned short Bs1[BN * LP];

  const int tid = threadIdx.x;
  const int wave = tid >> 6;
  const int lane = tid & 63;
  const int wm = wave >> 1, wn = wave & 1;

  int tm, tn, batch = 0, ks = 0;
  if constexpr (SWZ && MODE == MODE_ATT) {
    const int bid = blockIdx.x;
    const int xcd = bid & 7, j = bid >> 3;
    const int z = (j >> 4) * 8 + xcd;   // 0..47, z%8 == xcd
    const int tile = j & 15;
    tn = tile & 3;
    tm = tile >> 2;
    ks = z % KS;
    batch = z / KS;
  } else if constexpr (SWZ && MODE == MODE_OUTWS) {
    const int bid = blockIdx.x;
    const int xcd = bid & 7, j = bid >> 3;
    const int g = (j >> 6) * 8 + xcd;   // 0..23, g%8 == xcd
    const int idx = j & 63;
    batch = g >> 1;                     // head
    tm = idx >> 4;
    tn = (g & 1) * 16 + (idx & 15);
  } else {
    if constexpr (SWZ) {
      const int bid = blockIdx.x;
      const int xcd = bid & 7;
      const int k = bid >> 3;
      tn = k % ntn;
      tm = (k / ntn) * 8 + xcd;
    } else {
      tn = blockIdx.x;
      tm = blockIdx.y;
    }
    batch = blockIdx.z;
    if constexpr (KS > 1) { ks = batch % KS; batch /= KS; }
  }

  const long long m0 = (long long)tm * BM;
  const long long n0 = (long long)tn * BN;

  const unsigned short* Ab = (const unsigned short*)Av + (long long)batch * a_bs + (long long)ks * K;
  const unsigned short* Bb = (const unsigned short*)Bv + (long long)batch * b_bs + (long long)ks * K;

  f32x4 acc[4][4] = {};

  const int l15 = lane & 15;
  const int kq = (lane >> 4) * 8;
  const int r_in = lane >> 2;        // 0..15
  const int c8 = (lane & 3) * 8;     // 0,8,16,24

  auto stage = [&](unsigned short* Asb, unsigned short* Bsb, int k0) {
#pragma unroll
    for (int t = 0; t < 2; ++t) {
      const int rb = t * 64 + wave * 16;  // wave-uniform row base
      gll16(Ab + (m0 + rb + r_in) * (long long)lda + k0 + c8, &Asb[rb * LP]);
      gll16(Bb + (n0 + rb + r_in) * (long long)ldb + k0 + c8, &Bsb[rb * LP]);
    }
  };
  auto compute = [&](const unsigned short* Asb, const unsigned short* Bsb) {
    bf16x8 af[4], bfr[4];
#pragma unroll
    for (int t = 0; t < 4; ++t)
      af[t] = *(const bf16x8*)&Asb[(wm * 64 + t * 16 + l15) * LP + kq];
#pragma unroll
    for (int u = 0; u < 4; ++u)
      bfr[u] = *(const bf16x8*)&Bsb[(wn * 64 + u * 16 + l15) * LP + kq];
#pragma unroll
    for (int t = 0; t < 4; ++t)
#pragma unroll
      for (int u = 0; u < 4; ++u)
        acc[t][u] = __builtin_amdgcn_mfma_f32_16x16x32_bf16(af[t], bfr[u], acc[t][u], 0, 0, 0);
  };

  // Preload bias into registers BEFORE the pipelined loop so no vector-memory
  // op other than the staging glls is ever in flight inside the K-loop
  // (keeps the vmcnt(4) count exact).
  float bpre[4] = {};
  float aa = alpha;
  if constexpr (MODE == MODE_QCAT) {
    const float* bb = batch ? bias2 : bias;
    aa = batch ? alpha2 : alpha;
#pragma unroll
    for (int u = 0; u < 4; ++u) bpre[u] = bb[n0 + wn * 64 + u * 16 + l15];
  } else if constexpr (MODE == MODE_VT || MODE == MODE_OUT_BIAS) {
#pragma unroll
    for (int u = 0; u < 4; ++u) bpre[u] = bias[n0 + wn * 64 + u * 16 + l15];
  }

  // Prologue: stage tile 0, drain everything once, sync.
  stage(As0, Bs0, 0);
  VMCNT_0;
  BAR;

  const int NT = K >> 5;  // even for all shapes used (24/32/16/24)
  for (int t = 0; t < NT; t += 2) {
    stage(As1, Bs1, (t + 1) << 5);   // prefetch odd tile
    VMCNT_4;                          // wait even tile only; odd stays in flight
    BAR;
    compute(As0, Bs0);
    BAR;                              // everyone done reading As0/Bs0
    if (t + 2 < NT) {
      stage(As0, Bs0, (t + 2) << 5); // prefetch next even tile
      VMCNT_4;                        // wait odd tile only
    } else {
      VMCNT_0;
    }
    BAR;
    compute(As1, Bs1);
    BAR;                              // everyone done reading As1/Bs1
  }

  // Epilogue: D[m][n] with m_rel=(lane>>4)*4+r, n_rel=lane&15 per 16x16 tile
#pragma unroll
  for (int t = 0; t < 4; ++t) {
#pragma unroll
    for (int u = 0; u < 4; ++u) {
      const long long col = n0 + wn * 64 + u * 16 + l15;
#pragma unroll
      for (int r = 0; r < 4; ++r) {
        const long long row = m0 + wm * 64 + t * 16 + (lane >> 4) * 4 + r;
        float v = acc[t][u][r];
        if constexpr (MODE == MODE_QCAT) {
          v = (v + bpre[u]) * aa;
          const long long h = col >> 6, kk = col & 63, n = row >> 9, i = row & 511;
          ((unsigned short*)Cv + batch * c_bs)[((h * 512 + i) << 12) + (n << 6) + kk] = f2bf(v);
        } else if constexpr (MODE == MODE_VT) {
          v = v + bpre[u];
          const long long h = col >> 6, kk = col & 63, n = row >> 9, j = row & 511;
          ((unsigned short*)Cv)[(((h << 12) + (n << 6) + kk) << 9) + j] = f2bf(v);
        } else if constexpr (MODE == MODE_ATT) {
          float* p = &((float*)Cv)[((long long)batch << 18) + (row << 9) + col];
          if constexpr (KS > 1) atomicAdd(p, v); else *p = v;
        } else if constexpr (MODE == MODE_OUTWS) {
          const long long n = col >> 6, kk = col & 63;
          ((unsigned short*)Cv)[(n * 512 + row) * 768 + (long long)batch * 64 + kk] = f2bf(v);
        } else {  // MODE_OUT_BIAS
          ((float*)Cv)[row * 768 + col] = v + bpre[u];
        }
      }
    }
  }
}

// softmax over last dim: att fp32 [12][512][512] -> bf16
__global__ __launch_bounds__(256) void softmax_rows(const float* __restrict__ att,
                                                    unsigned short* __restrict__ outb) {
  const long long rowbase = (long long)blockIdx.x << 9;
  const int tid = threadIdx.x;
  float a = att[rowbase + tid];
  float b = att[rowbase + tid + 256];

  float m = fmaxf(a, b);
#pragma unroll
  for (int off = 32; off; off >>= 1) m = fmaxf(m, __shfl_down(m, off));
  __shared__ float redm[4];
  if ((tid & 63) == 0) redm[tid >> 6] = m;
  __syncthreads();
  m = fmaxf(fmaxf(redm[0], redm[1]), fmaxf(redm[2], redm[3]));

  const float e0 = __expf(a - m), e1 = __expf(b - m);
  float s = e0 + e1;
#pragma unroll
  for (int off = 32; off; off >>= 1) s += __shfl_down(s, off);
  __shared__ float reds[4];
  if ((tid & 63) == 0) reds[tid >> 6] = s;
  __syncthreads();
  s = reds[0] + reds[1] + reds[2] + reds[3];

  const float inv = 1.0f / s;
  outb[rowbase + tid] = f2bf(e0 * inv);
  outb[rowbase + tid + 256] = f2bf(e1 * inv);
}

// fp32 -> bf16, 8 elems/thread (n must be multiple of 2048)
__global__ __launch_bounds__(256) void cvt_bf16(const float* __restrict__ in,
                                                unsigned short* __restrict__ out) {
  const long long i = ((long long)blockIdx.x * 256 + threadIdx.x) * 8;
  const float4 a = *(const float4*)(in + i);
  const float4 b = *(const float4*)(in + i + 4);
  uint4 p;
  p.x = (unsigned)f2bf(a.x) | ((unsigned)f2bf(a.y) << 16);
  p.y = (unsigned)f2bf(a.z) | ((unsigned)f2bf(a.w) << 16);
  p.z = (unsigned)f2bf(b.x) | ((unsigned)f2bf(b.y) << 16);
  p.w = (unsigned)f2bf(b.z) | ((unsigned)f2bf(b.w) << 16);
  *(uint4*)(out + i) = p;
}

// fp32 -> bf16 for two big tensors in one launch (blockIdx.y picks tensor)
__global__ __launch_bounds__(256) void cvt_qk(
    const float* __restrict__ s0, const float* __restrict__ s1,
    unsigned short* __restrict__ d0, unsigned short* __restrict__ d1) {
  const float* s = blockIdx.y ? s1 : s0;
  unsigned short* d = blockIdx.y ? d1 : d0;
  const long long i = ((long long)blockIdx.x * 256 + threadIdx.x) * 8;
  const float4 a = *(const float4*)(s + i);
  const float4 b = *(const float4*)(s + i + 4);
  uint4 p;
  p.x = (unsigned)f2bf(a.x) | ((unsigned)f2bf(a.y) << 16);
  p.y = (unsigned)f2bf(a.z) | ((unsigned)f2bf(a.w) << 16);
  p.z = (unsigned)f2bf(b.x) | ((unsigned)f2bf(b.y) << 16);
  p.w = (unsigned)f2bf(b.z) | ((unsigned)f2bf(b.w) << 16);
  *(uint4*)(d + i) = p;
}

// fp32 -> bf16 for the four 768x768 weights in one launch
__global__ __launch_bounds__(256) void cvt_w4(
    const float* __restrict__ s0, const float* __restrict__ s1,
    const float* __restrict__ s2, const float* __restrict__ s3,
    unsigned short* __restrict__ d0, unsigned short* __restrict__ d1,
    unsigned short* __restrict__ d2, unsigned short* __restrict__ d3) {
  const float* s;
  unsigned short* d;
  switch (blockIdx.y) {
    case 0: s = s0; d = d0; break;
    case 1: s = s1; d = d1; break;
    case 2: s = s2; d = d2; break;
    default: s = s3; d = d3; break;
  }
  const long long i = ((long long)blockIdx.x * 256 + threadIdx.x) * 8;
  const float4 a = *(const float4*)(s + i);
  const float4 b = *(const float4*)(s + i + 4);
  uint4 p;
  p.x = (unsigned)f2bf(a.x) | ((unsigned)f2bf(a.y) << 16);
  p.y = (unsigned)f2bf(a.z) | ((unsigned)f2bf(a.w) << 16);
  p.z = (unsigned)f2bf(b.x) | ((unsigned)f2bf(b.y) << 16);
  p.w = (unsigned)f2bf(b.z) | ((unsigned)f2bf(b.w) << 16);
  *(uint4*)(d + i) = p;
}

extern "C" void kernel_launch(void* const* d_in, const int* in_sizes, int n_in,
                              void* d_out, int out_size, void* d_ws, size_t ws_size,
                              hipStream_t stream) {
  const float* query = (const float*)d_in[0];
  const float* key   = (const float*)d_in[1];
  const float* value = (const float*)d_in[2];
  const float* Wq = (const float*)d_in[3];
  const float* bq = (const float*)d_in[4];
  const float* Wk = (const float*)d_in[5];
  const float* bk = (const float*)d_in[6];
  const float* Wv = (const float*)d_in[7];
  const float* bv = (const float*)d_in[8];
  const float* Wo = (const float*)d_in[9];
  const float* bo = (const float*)d_in[10];
  float* out = (float*)d_out;

  char* ws = (char*)d_ws;
  unsigned short* q_ws  = (unsigned short*)(ws);               // 50,331,648 B
  unsigned short* k_ws  = (unsigned short*)(ws + 50331648);    // 50,331,648 B
  unsigned short* vt_ws = (unsigned short*)(ws + 100663296);   // 50,331,648 B
  float*          att   = (float*)(ws + 150994944);            // 12,582,912 B
  unsigned short* wo_b  = (unsigned short*)(ws + 163577856);   //  1,179,648 B
  // bf16 weight copies live in the att region (dead until the s2 memset)
  unsigned short* wq_b  = (unsigned short*)(ws + 150994944);
  unsigned short* wk_b  = (unsigned short*)(ws + 150994944 + 1179648);
  unsigned short* wv_b  = (unsigned short*)(ws + 150994944 + 2359296);
  unsigned short* att_b = k_ws;   // k_ws dead after s2
  unsigned short* out_ws = q_ws;  // q_ws dead after s2
  // bf16 input scratch: d_out is dead until s5 (fully overwritten there)
  unsigned short* xb0 = (unsigned short*)d_out;                 // 50,331,648 B
  unsigned short* xb1 = (unsigned short*)d_out + 25165824;      // 50,331,648 B

  const dim3 blk(256);

  // s0: all four weights fp32 -> bf16 (589824 elems = 288 * 2048 each)
  cvt_w4<<<dim3(288, 4), blk, 0, stream>>>(Wo, Wq, Wk, Wv, wo_b, wq_b, wk_b, wv_b);

  // s1a: query+key fp32 -> bf16 in one launch (25,165,824 elems = 12288*2048 each)
  cvt_qk<<<dim3(12288, 2), blk, 0, stream>>>(query, key, xb0, xb1);

  // s1b: Q and K projections batched (z=2): A,B,C batch-strided, per-batch bias/alpha
  gemm_bt<MODE_QCAT, true, 1><<<dim3(1536, 1, 2), blk, 0, stream>>>(
      xb0, wq_b, bq, q_ws, 768, 768, 768, 25165824LL, 589824LL, 0.015625f, 6,
      bk, 1.0f, 25165824LL);

  // s1c: value cvt + V projection
  cvt_bf16<<<12288, blk, 0, stream>>>(value, xb0);
  gemm_bt<MODE_VT, true, 1><<<dim3(1536, 1, 1), blk, 0, stream>>>(
      xb0, wv_b, bv, vt_ws, 768, 768, 768, 0, 0, 1.0f, 6, nullptr, 0.0f, 0);

  // s2: tied scores, per-head [512 x 4096] @ [512 x 4096]^T, split-K x4.
  //     Locality map: 16 tiles of one z=(head,ks) share 2 MB -> one XCD L2.
  hipMemsetAsync(att, 0, 12582912, stream);
  gemm_bt<MODE_ATT, true, 4><<<dim3(768, 1, 1), blk, 0, stream>>>(
      q_ws, k_ws, nullptr, att, 1024, 4096, 4096, 2097152LL, 2097152LL, 1.0f, 0,
      nullptr, 0.0f, 0);

  // s3: softmax
  softmax_rows<<<6144, blk, 0, stream>>>(att, att_b);

  // s4: per-head att @ Vt^T -> out_ws [(n*512+i)][h*64+k].
  //     Locality map: 64 tiles of one (head, N-half) share 2.5 MB -> one XCD L2.
  gemm_bt<MODE_OUTWS, true, 1><<<dim3(1536, 1, 1), blk, 0, stream>>>(
      att_b, vt_ws, nullptr, out_ws, 512, 512, 512, 262144LL, 2097152LL, 1.0f, 0,
      nullptr, 0.0f, 0);

  // s5: output projection -> fp32 d_out, generic XCD swizzle
  gemm_bt<MODE_OUT_BIAS, true, 1><<<dim3(1536, 1, 1), blk, 0, stream>>>(
      out_ws, wo_b, bo, out, 768, 768, 768, 0, 0, 1.0f, 6, nullptr, 0.0f, 0);
}